// Round 7
// baseline (823.205 us; speedup 1.0000x reference)
//
#include <hip/hip_runtime.h>

#define NN 50000
#define NE 800000
#define NG 256
#define NBUCKET 64

// bucketed CSR build params
#define NBKT 391      // node buckets of 128 (391*128 = 50048 >= NN)
#define ABLK 391      // A-pass blocks
#define ASLICE 2048   // edges per A-pass block (391*2048 >= NE)
#define BCAP 2560     // LDS staging capacity per bucket (mean 2046, +11 sigma)

// ---------------- prologue ----------------
// zero part buckets + done counters
__global__ void k_init(float* part, int* dctr) {
    int i = blockIdx.x * blockDim.x + threadIdx.x;
    if (i < NBUCKET * 256) part[i] = 0.f;
    if (i < 8) dctr[i] = 0;
}

// A1: per-(block,bucket) edge counts via LDS histogram
__global__ void kA1(const int* __restrict__ col, int* __restrict__ bb, int e) {
    __shared__ int cnt[NBKT];
    for (int j = threadIdx.x; j < NBKT; j += 256) cnt[j] = 0;
    __syncthreads();
    int start = blockIdx.x * ASLICE;
    int end = min(start + ASLICE, e);
    for (int i = start + threadIdx.x; i < end; i += 256)
        atomicAdd(&cnt[col[i] >> 7], 1);
    __syncthreads();
    for (int j = threadIdx.x; j < NBKT; j += 256) bb[blockIdx.x * NBKT + j] = cnt[j];
}

// A2a: per-bucket exclusive scan over blocks (in place), bucket totals out
__global__ void kA2a(int* __restrict__ bb, int* __restrict__ totals) {
    __shared__ int v[ABLK];
    int k = blockIdx.x;
    for (int b = threadIdx.x; b < ABLK; b += 256) v[b] = bb[b * NBKT + k];
    __syncthreads();
    if (threadIdx.x == 0) {
        int run = 0;
        for (int b = 0; b < ABLK; ++b) { int t = v[b]; v[b] = run; run += t; }
        totals[k] = run;
    }
    __syncthreads();
    for (int b = threadIdx.x; b < ABLK; b += 256) bb[b * NBKT + k] = v[b];
}

// A2b: exclusive scan of bucket totals -> bucketbase[NBKT+1]
__global__ void kA2b(const int* __restrict__ totals, int* __restrict__ bucketbase) {
    __shared__ int v[NBKT];
    for (int j = threadIdx.x; j < NBKT; j += 256) v[j] = totals[j];
    __syncthreads();
    if (threadIdx.x == 0) {
        int run = 0;
        for (int k = 0; k < NBKT; ++k) { int t = v[k]; v[k] = run; run += t; }
        bucketbase[NBKT] = run;
    }
    __syncthreads();
    for (int j = threadIdx.x; j < NBKT; j += 256) bucketbase[j] = v[j];
}

// A3: scatter edges into per-(block,bucket) private contiguous staging ranges
// staging entry: { row | (col&127)<<16 , ew_bits }  (row < 65536)
__global__ void kA3(const int* __restrict__ row, const int* __restrict__ col,
                    const float* __restrict__ ew, const int* __restrict__ bb,
                    const int* __restrict__ bucketbase, int2* __restrict__ staging, int e) {
    __shared__ int cur[NBKT];
    for (int j = threadIdx.x; j < NBKT; j += 256)
        cur[j] = bucketbase[j] + bb[blockIdx.x * NBKT + j];
    __syncthreads();
    int start = blockIdx.x * ASLICE;
    int end = min(start + ASLICE, e);
    for (int i = start + threadIdx.x; i < end; i += 256) {
        int c = col[i];
        int p = atomicAdd(&cur[c >> 7], 1);
        staging[p] = make_int2(row[i] | ((c & 127) << 16), __float_as_int(ew[i]));
    }
}

// B: per-bucket LDS counting sort -> csr {src, raw_ew}, ptr, deg->dis
__global__ void __launch_bounds__(256) kB(const int* __restrict__ bucketbase,
                                          const int2* __restrict__ staging,
                                          int2* __restrict__ csr, int* __restrict__ ptr,
                                          float* __restrict__ dis, int n) {
    __shared__ int2 st[BCAP];
    __shared__ int2 outb[BCAP];
    __shared__ int hist[129];
    __shared__ int cur[128];
    int k = blockIdx.x, t = threadIdx.x;
    int base = bucketbase[k], cnt = bucketbase[k + 1] - base;
    int node0 = k << 7;
    int ncov = min(128, n - node0);
    if (t < 129) hist[t] = 0;
    __syncthreads();
    if (cnt <= BCAP) {
        for (int i = t; i < cnt; i += 256) {
            int2 v = staging[base + i];
            st[i] = v;
            atomicAdd(&hist[v.x >> 16], 1);
        }
        __syncthreads();
        if (t == 0) {
            int run = 0;
            for (int j = 0; j < 128; ++j) { int h = hist[j]; hist[j] = run; run += h; }
            hist[128] = run;
        }
        __syncthreads();
        if (t < 128) cur[t] = hist[t];
        if (t < ncov) ptr[node0 + t] = base + hist[t];
        __syncthreads();
        for (int i = t; i < cnt; i += 256) {
            int2 v = st[i];
            int j = v.x >> 16;
            int p = atomicAdd(&cur[j], 1);
            outb[p] = make_int2(v.x & 0xFFFF, v.y);
        }
        __syncthreads();
        for (int i = t; i < cnt; i += 256) csr[base + i] = outb[i];
        if (t < ncov) {
            float s = 1.f;
            int a = hist[t], b2 = hist[t + 1];
            for (int p = a; p < b2; ++p) s += __int_as_float(outb[p].y);
            dis[node0 + t] = rsqrtf(s);
        }
    } else {
        // fallback (statistically unreachable): global two-sweep
        for (int i = t; i < cnt; i += 256) atomicAdd(&hist[staging[base + i].x >> 16], 1);
        __syncthreads();
        if (t == 0) {
            int run = 0;
            for (int j = 0; j < 128; ++j) { int h = hist[j]; hist[j] = run; run += h; }
            hist[128] = run;
        }
        __syncthreads();
        if (t < 128) cur[t] = hist[t];
        if (t < ncov) ptr[node0 + t] = base + hist[t];
        __syncthreads();
        for (int i = t; i < cnt; i += 256) {
            int2 v = staging[base + i];
            int j = v.x >> 16;
            int p = atomicAdd(&cur[j], 1);
            csr[base + p] = make_int2(v.x & 0xFFFF, v.y);
        }
        __threadfence_block();
        __syncthreads();
        if (t < ncov) {
            float s = 1.f;
            int a = hist[t], b2 = hist[t + 1];
            for (int p = a; p < b2; ++p) s += __int_as_float(csr[base + p].y);
            dis[node0 + t] = rsqrtf(s);
        }
    }
    if (k == gridDim.x - 1 && t == 0) ptr[n] = bucketbase[NBKT];
}

// csr[p].y: raw ew -> dis[src]*ew*dis[c]  (in place)
__global__ void k_scale(const int* __restrict__ ptr, int2* __restrict__ csr,
                        const float* __restrict__ dis, int n) {
    int i = blockIdx.x * blockDim.x + threadIdx.x;
    if (i >= n) return;
    float dc = dis[i];
    int p1 = ptr[i + 1];
    for (int p = ptr[i]; p < p1; ++p) {
        int2 v = csr[p];
        csr[p].y = __float_as_int(dis[v.x] * __int_as_float(v.y) * dc);
    }
}

// ---------------- embedded BN finalize (last-block pattern) ----------------
__device__ __forceinline__ void finalize_tail(float* part, int* dctr,
                                              const float* gmv, const float* btv,
                                              float* oscl, float* oshf,
                                              int dout, int n, int tid) {
    __threadfence();
    __shared__ int lastflag;
    if (tid == 0) lastflag = (atomicAdd(dctr, 1) == (int)gridDim.x - 1);
    __syncthreads();
    if (lastflag && tid < dout) {
        float s = 0.f, q = 0.f;
        for (int b = 0; b < NBUCKET; ++b) {
            s += __hip_atomic_load(&part[b * 256 + tid], __ATOMIC_RELAXED, __HIP_MEMORY_SCOPE_AGENT);
            q += __hip_atomic_load(&part[b * 256 + 128 + tid], __ATOMIC_RELAXED, __HIP_MEMORY_SCOPE_AGENT);
            __hip_atomic_store(&part[b * 256 + tid], 0.f, __ATOMIC_RELAXED, __HIP_MEMORY_SCOPE_AGENT);
            __hip_atomic_store(&part[b * 256 + 128 + tid], 0.f, __ATOMIC_RELAXED, __HIP_MEMORY_SCOPE_AGENT);
        }
        float mu = s / n;
        float var = q / n - mu * mu;
        float a = gmv[tid] * rsqrtf(var + 1e-5f);
        oscl[tid] = a;
        oshf[tid] = btv[tid] - mu * a;
    }
}

// ---------------- gather ----------------
// POSTAFF (L2/L3/L4): out = sc*A + sh*(dis^2 + sum w)   [BN linear, hoisted]
// PREAFF  (L5): per-edge relu(sc*u+sh)
// EPI     (L1): out = relu(A + bias), channel stats -> buckets + embedded finalize
template <int D, int POSTAFF, int PREAFF, int EPI>
__global__ void k_gather(const float* __restrict__ src, const int* __restrict__ ptr,
                         const int2* __restrict__ csr, const float* __restrict__ dis,
                         const float* __restrict__ scale, const float* __restrict__ shift,
                         const float* __restrict__ bias, float* __restrict__ part,
                         int* dctr, const float* __restrict__ gmv, const float* __restrict__ btv,
                         float* oscl, float* oshf,
                         float* __restrict__ out, int n) {
    const int TPN = D / 4;
    __shared__ float ls[EPI ? D : 1], lq[EPI ? D : 1];
    int tid = threadIdx.x;
    if (EPI) {
        if (tid < D) { ls[tid] = 0.f; lq[tid] = 0.f; }
        __syncthreads();
    }
    int t = blockIdx.x * blockDim.x + tid;
    int node = t / TPN;
    int l4 = t - node * TPN;
    bool valid = node < n;
    int nc = valid ? node : n - 1;

    float4 sc = {0,0,0,0}, sh = {0,0,0,0};
    if (POSTAFF || PREAFF) {
        sc = ((const float4*)scale)[l4];
        sh = ((const float4*)shift)[l4];
    }
    const float4* s4 = (const float4*)src;
    float d = dis[nc];
    float w0 = d * d;
    float4 v = s4[nc * TPN + l4];
    if (PREAFF) {
        v.x = fmaxf(sc.x * v.x + sh.x, 0.f); v.y = fmaxf(sc.y * v.y + sh.y, 0.f);
        v.z = fmaxf(sc.z * v.z + sh.z, 0.f); v.w = fmaxf(sc.w * v.w + sh.w, 0.f);
    }
    float4 acc = { w0 * v.x, w0 * v.y, w0 * v.z, w0 * v.w };
    float sumw = w0;
    int p0 = ptr[nc], p1 = ptr[nc + 1];
    int p = p0;
    for (; p + 4 <= p1; p += 4) {
        int2 c0 = csr[p], c1 = csr[p+1], c2 = csr[p+2], c3 = csr[p+3];
        float e0 = __int_as_float(c0.y), e1 = __int_as_float(c1.y);
        float e2 = __int_as_float(c2.y), e3 = __int_as_float(c3.y);
        float4 u0 = s4[c0.x * TPN + l4];
        float4 u1 = s4[c1.x * TPN + l4];
        float4 u2 = s4[c2.x * TPN + l4];
        float4 u3 = s4[c3.x * TPN + l4];
        if (PREAFF) {
            u0.x = fmaxf(sc.x*u0.x+sh.x,0.f); u0.y = fmaxf(sc.y*u0.y+sh.y,0.f);
            u0.z = fmaxf(sc.z*u0.z+sh.z,0.f); u0.w = fmaxf(sc.w*u0.w+sh.w,0.f);
            u1.x = fmaxf(sc.x*u1.x+sh.x,0.f); u1.y = fmaxf(sc.y*u1.y+sh.y,0.f);
            u1.z = fmaxf(sc.z*u1.z+sh.z,0.f); u1.w = fmaxf(sc.w*u1.w+sh.w,0.f);
            u2.x = fmaxf(sc.x*u2.x+sh.x,0.f); u2.y = fmaxf(sc.y*u2.y+sh.y,0.f);
            u2.z = fmaxf(sc.z*u2.z+sh.z,0.f); u2.w = fmaxf(sc.w*u2.w+sh.w,0.f);
            u3.x = fmaxf(sc.x*u3.x+sh.x,0.f); u3.y = fmaxf(sc.y*u3.y+sh.y,0.f);
            u3.z = fmaxf(sc.z*u3.z+sh.z,0.f); u3.w = fmaxf(sc.w*u3.w+sh.w,0.f);
        }
        acc.x += e0*u0.x + e1*u1.x + e2*u2.x + e3*u3.x;
        acc.y += e0*u0.y + e1*u1.y + e2*u2.y + e3*u3.y;
        acc.z += e0*u0.z + e1*u1.z + e2*u2.z + e3*u3.z;
        acc.w += e0*u0.w + e1*u1.w + e2*u2.w + e3*u3.w;
        if (POSTAFF) sumw += e0 + e1 + e2 + e3;
    }
    for (; p < p1; ++p) {
        int2 ce = csr[p];
        float w = __int_as_float(ce.y);
        float4 u = s4[ce.x * TPN + l4];
        if (PREAFF) {
            u.x = fmaxf(sc.x*u.x+sh.x,0.f); u.y = fmaxf(sc.y*u.y+sh.y,0.f);
            u.z = fmaxf(sc.z*u.z+sh.z,0.f); u.w = fmaxf(sc.w*u.w+sh.w,0.f);
        }
        acc.x += w*u.x; acc.y += w*u.y; acc.z += w*u.z; acc.w += w*u.w;
        if (POSTAFF) sumw += w;
    }
    if (POSTAFF) {
        acc.x = sc.x * acc.x + sh.x * sumw;
        acc.y = sc.y * acc.y + sh.y * sumw;
        acc.z = sc.z * acc.z + sh.z * sumw;
        acc.w = sc.w * acc.w + sh.w * sumw;
    }
    if (EPI) {
        float4 b = ((const float4*)bias)[l4];
        acc.x = fmaxf(acc.x + b.x, 0.f);
        acc.y = fmaxf(acc.y + b.y, 0.f);
        acc.z = fmaxf(acc.z + b.z, 0.f);
        acc.w = fmaxf(acc.w + b.w, 0.f);
        if (valid) ((float4*)out)[nc * TPN + l4] = acc;
        float s0 = valid ? acc.x : 0.f, s1 = valid ? acc.y : 0.f;
        float s2 = valid ? acc.z : 0.f, s3 = valid ? acc.w : 0.f;
        float q0 = s0*s0, q1 = s1*s1, q2 = s2*s2, q3 = s3*s3;
        for (int off = TPN; off < 64; off <<= 1) {
            s0 += __shfl_down(s0, off, 64); s1 += __shfl_down(s1, off, 64);
            s2 += __shfl_down(s2, off, 64); s3 += __shfl_down(s3, off, 64);
            q0 += __shfl_down(q0, off, 64); q1 += __shfl_down(q1, off, 64);
            q2 += __shfl_down(q2, off, 64); q3 += __shfl_down(q3, off, 64);
        }
        int lane = tid & 63;
        if (lane < TPN) {
            atomicAdd(&ls[4*lane+0], s0); atomicAdd(&ls[4*lane+1], s1);
            atomicAdd(&ls[4*lane+2], s2); atomicAdd(&ls[4*lane+3], s3);
            atomicAdd(&lq[4*lane+0], q0); atomicAdd(&lq[4*lane+1], q1);
            atomicAdd(&lq[4*lane+2], q2); atomicAdd(&lq[4*lane+3], q3);
        }
        __syncthreads();
        int bkt = (blockIdx.x & (NBUCKET - 1)) * 256;
        if (tid < D) {
            atomicAdd(&part[bkt + tid], ls[tid]);
            atomicAdd(&part[bkt + 128 + tid], lq[tid]);
        }
        finalize_tail(part, dctr, gmv, btv, oscl, oshf, D, n, tid);
    } else {
        if (valid) ((float4*)out)[nc * TPN + l4] = acc;
    }
}

// ---------------- node-blocked GEMM: NPT nodes x 4 outputs per thread ----------------
template <int DIN, int DOUT, int RELU, int EPI, int NPT>
__global__ void k_gemm(const float* __restrict__ h, const float* __restrict__ W,
                       const float* __restrict__ bias, float* __restrict__ part,
                       int* dctr, const float* __restrict__ gmv, const float* __restrict__ btv,
                       float* oscl, float* oshf,
                       float* __restrict__ m, int n) {
    const int TPN = DOUT / 4;
    const int GPB = 256 / TPN;
    __shared__ float Wl[DIN * DOUT];
    __shared__ float ls[EPI ? DOUT : 1], lq[EPI ? DOUT : 1];
    int tid = threadIdx.x;
    for (int i = tid; i < DIN * DOUT / 4; i += 256)
        ((float4*)Wl)[i] = ((const float4*)W)[i];
    if (EPI && tid < DOUT) { ls[tid] = 0.f; lq[tid] = 0.f; }
    __syncthreads();

    int jq = tid % TPN;
    int group = tid / TPN;
    int node0 = (blockIdx.x * GPB + group) * NPT;
    const float4* h4 = (const float4*)h;
    int hb[NPT];
    bool val[NPT];
#pragma unroll
    for (int i = 0; i < NPT; ++i) {
        int nd = node0 + i;
        val[i] = nd < n;
        hb[i] = (val[i] ? nd : n - 1) * (DIN / 4);
    }
    float4 acc[NPT];
#pragma unroll
    for (int i = 0; i < NPT; ++i) acc[i] = {0.f, 0.f, 0.f, 0.f};

#pragma unroll 4
    for (int k4 = 0; k4 < DIN / 4; ++k4) {
        const float* wb = &Wl[(k4 * 4) * DOUT + jq * 4];
        float4 w0 = *(const float4*)(wb);
        float4 w1 = *(const float4*)(wb + DOUT);
        float4 w2 = *(const float4*)(wb + 2 * DOUT);
        float4 w3 = *(const float4*)(wb + 3 * DOUT);
#pragma unroll
        for (int i = 0; i < NPT; ++i) {
            float4 hv = h4[hb[i] + k4];
            acc[i].x += hv.x*w0.x + hv.y*w1.x + hv.z*w2.x + hv.w*w3.x;
            acc[i].y += hv.x*w0.y + hv.y*w1.y + hv.z*w2.y + hv.w*w3.y;
            acc[i].z += hv.x*w0.z + hv.y*w1.z + hv.z*w2.z + hv.w*w3.z;
            acc[i].w += hv.x*w0.w + hv.y*w1.w + hv.z*w2.w + hv.w*w3.w;
        }
    }

    float4 bv = {0,0,0,0};
    if (EPI) bv = ((const float4*)bias)[jq];
    float4 sv = {0,0,0,0}, qv = {0,0,0,0};
#pragma unroll
    for (int i = 0; i < NPT; ++i) {
        float4 a = acc[i];
        if (EPI) {
            a.x += bv.x; a.y += bv.y; a.z += bv.z; a.w += bv.w;
            if (RELU) {
                a.x = fmaxf(a.x, 0.f); a.y = fmaxf(a.y, 0.f);
                a.z = fmaxf(a.z, 0.f); a.w = fmaxf(a.w, 0.f);
            }
        }
        if (val[i]) {
            ((float4*)m)[(node0 + i) * TPN + jq] = a;
            if (EPI) {
                sv.x += a.x; sv.y += a.y; sv.z += a.z; sv.w += a.w;
                qv.x += a.x*a.x; qv.y += a.y*a.y; qv.z += a.z*a.z; qv.w += a.w*a.w;
            }
        }
    }
    if (EPI) {
        for (int off = TPN; off < 64; off <<= 1) {
            sv.x += __shfl_down(sv.x, off, 64); sv.y += __shfl_down(sv.y, off, 64);
            sv.z += __shfl_down(sv.z, off, 64); sv.w += __shfl_down(sv.w, off, 64);
            qv.x += __shfl_down(qv.x, off, 64); qv.y += __shfl_down(qv.y, off, 64);
            qv.z += __shfl_down(qv.z, off, 64); qv.w += __shfl_down(qv.w, off, 64);
        }
        int lane = tid & 63;
        if (lane < TPN) {
            atomicAdd(&ls[4*lane+0], sv.x); atomicAdd(&ls[4*lane+1], sv.y);
            atomicAdd(&ls[4*lane+2], sv.z); atomicAdd(&ls[4*lane+3], sv.w);
            atomicAdd(&lq[4*lane+0], qv.x); atomicAdd(&lq[4*lane+1], qv.y);
            atomicAdd(&lq[4*lane+2], qv.z); atomicAdd(&lq[4*lane+3], qv.w);
        }
        __syncthreads();
        int bkt = (blockIdx.x & (NBUCKET - 1)) * 256;
        if (tid < DOUT) {
            atomicAdd(&part[bkt + tid], ls[tid]);
            atomicAdd(&part[bkt + 128 + tid], lq[tid]);
        }
        finalize_tail(part, dctr, gmv, btv, oscl, oshf, DOUT, n, tid);
    }
}

// ---------------- fused pool (BN5 inline) + MLP head, atomic-free ----------------
__global__ void k_poolhead(const float* __restrict__ h, const int* __restrict__ batch,
                           const float* __restrict__ scale, const float* __restrict__ shift,
                           const float* __restrict__ fc1w, const float* __restrict__ fc1b,
                           const float* __restrict__ fc2w, const float* __restrict__ fc2b,
                           float* __restrict__ out, int n) {
    __shared__ float tmp[256];
    __shared__ float pl[128];
    int g = blockIdx.x;
    int tid = threadIdx.x;
    int j = tid & 127, part = tid >> 7;
    int a = 0, b = n;
    while (a < b) { int mid = (a + b) >> 1; if (batch[mid] < g) a = mid + 1; else b = mid; }
    int lo = a;
    b = n;
    while (a < b) { int mid = (a + b) >> 1; if (batch[mid] < g + 1) a = mid + 1; else b = mid; }
    int hi = a;

    float acc = 0.f;
    for (int node = lo + part; node < hi; node += 2) acc += h[(long)node * 128 + j];
    tmp[tid] = acc;
    __syncthreads();
    if (tid < 128) {
        float cnt = (float)(hi - lo);
        float p = scale[tid] * (tmp[tid] + tmp[tid + 128]) + shift[tid] * cnt;
        pl[tid] = fmaxf(p, 0.f);
    }
    __syncthreads();
    if (tid < 64) {
        float v1 = fc1b[tid];
        for (int k = 0; k < 128; ++k) v1 += pl[k] * fc1w[k * 64 + tid];
        v1 = fmaxf(v1, 0.f);
        float v = v1 * fc2w[tid];
        for (int off = 32; off > 0; off >>= 1) v += __shfl_down(v, off, 64);
        if (tid == 0) out[g] = v + fc2b[0];
    }
}

// ---------------- driver ----------------
extern "C" void kernel_launch(void* const* d_in, const int* in_sizes, int n_in,
                              void* d_out, int out_size, void* d_ws, size_t ws_size,
                              hipStream_t stream) {
    const float* x     = (const float*)d_in[0];
    const int*   ei    = (const int*)d_in[1];
    const float* ew    = (const float*)d_in[2];
    const int*   batch = (const int*)d_in[3];
    const float *W[5], *b[5], *gm[5], *bt[5];
    for (int i = 0; i < 5; ++i) {
        W[i]  = (const float*)d_in[4 + 4 * i];
        b[i]  = (const float*)d_in[5 + 4 * i];
        gm[i] = (const float*)d_in[6 + 4 * i];
        bt[i] = (const float*)d_in[7 + 4 * i];
    }
    const float* fc1w = (const float*)d_in[24];
    const float* fc1b = (const float*)d_in[25];
    const float* fc2w = (const float*)d_in[26];
    const float* fc2b = (const float*)d_in[27];
    float* out = (float*)d_out;

    // workspace layout
    char* wsb = (char*)d_ws;
    float* dis    = (float*)wsb;  wsb += sizeof(float) * NN;
    int*   ptr    = (int*)wsb;    wsb += sizeof(int) * (NN + 4);
    int*   bb     = (int*)wsb;    wsb += sizeof(int) * ABLK * NBKT;
    int*   totals = (int*)wsb;    wsb += sizeof(int) * (NBKT + 1);
    int*   bbase  = (int*)wsb;    wsb += sizeof(int) * (NBKT + 3);
    int2*  staging= (int2*)wsb;   wsb += sizeof(int2) * NE;
    int2*  csr    = (int2*)wsb;   wsb += sizeof(int2) * NE;
    float* part   = (float*)wsb;  wsb += sizeof(float) * NBUCKET * 256;
    int*   dctr   = (int*)wsb;    wsb += sizeof(int) * 8;
    float* scl    = (float*)wsb;  wsb += sizeof(float) * 5 * 128;
    float* shf    = (float*)wsb;  wsb += sizeof(float) * 5 * 128;
    float* buf1   = (float*)wsb;  wsb += sizeof(float) * (long)NN * 128;
    float* buf2   = (float*)wsb;  wsb += sizeof(float) * (long)NN * 128;

    const int* row = ei;
    const int* col = ei + NE;
    const int B = 256;
    const int NB_N = (NN + B - 1) / B;   // 196

    // prologue: bucketed CSR build (atomic-light, coalesced)
    k_init<<<(NBUCKET * 256 + B - 1) / B, B, 0, stream>>>(part, dctr);
    kA1<<<ABLK, B, 0, stream>>>(col, bb, NE);
    kA2a<<<NBKT, B, 0, stream>>>(bb, totals);
    kA2b<<<1, B, 0, stream>>>(totals, bbase);
    kA3<<<ABLK, B, 0, stream>>>(row, col, ew, bb, bbase, staging, NE);
    kB<<<NBKT, B, 0, stream>>>(bbase, staging, csr, ptr, dis, NN);
    k_scale<<<NB_N, B, 0, stream>>>(ptr, csr, dis, NN);

    auto grid4 = [](long threads) { return (int)((threads + 255) / 256); };
    auto ggrid = [](int npb) { return (NN + npb - 1) / npb; };

    // L1: gemm 128->16 (NPT=2), gather16 + bias+relu+stats+finalize
    k_gemm<128, 16, 0, 0, 2><<<ggrid((256/4)*2), B, 0, stream>>>(x, W[0], b[0], nullptr,
                                                                 nullptr, nullptr, nullptr, nullptr, nullptr, buf1, NN);
    k_gather<16, 0, 0, 1><<<grid4((long)NN * 4), B, 0, stream>>>(buf1, ptr, csr, dis,
                                                                 nullptr, nullptr, b[0], part,
                                                                 dctr + 0, gm[0], bt[0], scl + 0, shf + 0, buf2, NN);

    // L2: gather16 (BN1 hoisted), gemm 16->32 + bias+relu+stats+finalize
    k_gather<16, 1, 0, 0><<<grid4((long)NN * 4), B, 0, stream>>>(buf2, ptr, csr, dis,
                                                                 scl + 0, shf + 0, nullptr, nullptr,
                                                                 nullptr, nullptr, nullptr, nullptr, nullptr, buf1, NN);
    k_gemm<16, 32, 1, 1, 4><<<ggrid((256/8)*4), B, 0, stream>>>(buf1, W[1], b[1], part,
                                                                dctr + 1, gm[1], bt[1], scl + 128, shf + 128, buf2, NN);

    // L3: gather32 (BN2 hoisted), gemm 32->64 + bias+relu+stats+finalize
    k_gather<32, 1, 0, 0><<<grid4((long)NN * 8), B, 0, stream>>>(buf2, ptr, csr, dis,
                                                                 scl + 128, shf + 128, nullptr, nullptr,
                                                                 nullptr, nullptr, nullptr, nullptr, nullptr, buf1, NN);
    k_gemm<32, 64, 1, 1, 4><<<ggrid((256/16)*4), B, 0, stream>>>(buf1, W[2], b[2], part,
                                                                 dctr + 2, gm[2], bt[2], scl + 256, shf + 256, buf2, NN);

    // L4: gather64 (BN3 hoisted), gemm 64->64 + bias+stats+finalize (relu post-BN)
    k_gather<64, 1, 0, 0><<<grid4((long)NN * 16), B, 0, stream>>>(buf2, ptr, csr, dis,
                                                                  scl + 256, shf + 256, nullptr, nullptr,
                                                                  nullptr, nullptr, nullptr, nullptr, nullptr, buf1, NN);
    k_gemm<64, 64, 0, 1, 4><<<ggrid((256/16)*4), B, 0, stream>>>(buf1, W[3], b[3], part,
                                                                 dctr + 3, gm[3], bt[3], scl + 384, shf + 384, buf2, NN);

    // L5: gather64 (BN4 + relu per-edge), gemm 64->128 + bias+stats+finalize
    k_gather<64, 0, 1, 0><<<grid4((long)NN * 16), B, 0, stream>>>(buf2, ptr, csr, dis,
                                                                  scl + 384, shf + 384, nullptr, nullptr,
                                                                  nullptr, nullptr, nullptr, nullptr, nullptr, buf1, NN);
    k_gemm<64, 128, 0, 1, 4><<<ggrid((256/32)*4), B, 0, stream>>>(buf1, W[4], b[4], part,
                                                                  dctr + 4, gm[4], bt[4], scl + 512, shf + 512, buf2, NN);

    // fused pool (BN5) + head
    k_poolhead<<<NG, 256, 0, stream>>>(buf2, batch, scl + 512, shf + 512,
                                       fc1w, fc1b, fc2w, fc2b, out, NN);
}

// Round 8
// 440.746 us; speedup vs baseline: 1.8678x; 1.8678x over previous
//
#include <hip/hip_runtime.h>

#define NN 50000
#define NE 800000
#define NG 256
#define NBUCKET 16
#define PARTSZ (NBUCKET * 256)

// bucketed CSR build params
#define NBKT 391      // node buckets of 128 (391*128 = 50048 >= NN)
#define ABLK 391      // A-pass blocks
#define ASLICE 2048   // edges per A-pass block (391*2048 >= NE)
#define BCAP 2560     // LDS staging capacity per bucket (mean 2046, +11 sigma)

// ---------------- prologue ----------------
// zero the 5 per-layer stats regions
__global__ void k_init(float* part) {
    int i = blockIdx.x * blockDim.x + threadIdx.x;
    if (i < 5 * PARTSZ) part[i] = 0.f;
}

// A1: per-(block,bucket) edge counts via LDS histogram
__global__ void kA1(const int* __restrict__ col, int* __restrict__ bb, int e) {
    __shared__ int cnt[NBKT];
    for (int j = threadIdx.x; j < NBKT; j += 256) cnt[j] = 0;
    __syncthreads();
    int start = blockIdx.x * ASLICE;
    int end = min(start + ASLICE, e);
    for (int i = start + threadIdx.x; i < end; i += 256)
        atomicAdd(&cnt[col[i] >> 7], 1);
    __syncthreads();
    for (int j = threadIdx.x; j < NBKT; j += 256) bb[blockIdx.x * NBKT + j] = cnt[j];
}

// A2a: per-bucket exclusive scan over blocks (in place), bucket totals out
__global__ void kA2a(int* __restrict__ bb, int* __restrict__ totals) {
    __shared__ int v[ABLK];
    int k = blockIdx.x;
    for (int b = threadIdx.x; b < ABLK; b += 256) v[b] = bb[b * NBKT + k];
    __syncthreads();
    if (threadIdx.x == 0) {
        int run = 0;
        for (int b = 0; b < ABLK; ++b) { int t = v[b]; v[b] = run; run += t; }
        totals[k] = run;
    }
    __syncthreads();
    for (int b = threadIdx.x; b < ABLK; b += 256) bb[b * NBKT + k] = v[b];
}

// A2b: exclusive scan of bucket totals -> bucketbase[NBKT+1]
__global__ void kA2b(const int* __restrict__ totals, int* __restrict__ bucketbase) {
    __shared__ int v[NBKT];
    for (int j = threadIdx.x; j < NBKT; j += 256) v[j] = totals[j];
    __syncthreads();
    if (threadIdx.x == 0) {
        int run = 0;
        for (int k = 0; k < NBKT; ++k) { int t = v[k]; v[k] = run; run += t; }
        bucketbase[NBKT] = run;
    }
    __syncthreads();
    for (int j = threadIdx.x; j < NBKT; j += 256) bucketbase[j] = v[j];
}

// A3: scatter edges into per-(block,bucket) private contiguous staging ranges
// staging entry: { row | (col&127)<<16 , ew_bits }  (row < 65536)
__global__ void kA3(const int* __restrict__ row, const int* __restrict__ col,
                    const float* __restrict__ ew, const int* __restrict__ bb,
                    const int* __restrict__ bucketbase, int2* __restrict__ staging, int e) {
    __shared__ int cur[NBKT];
    for (int j = threadIdx.x; j < NBKT; j += 256)
        cur[j] = bucketbase[j] + bb[blockIdx.x * NBKT + j];
    __syncthreads();
    int start = blockIdx.x * ASLICE;
    int end = min(start + ASLICE, e);
    for (int i = start + threadIdx.x; i < end; i += 256) {
        int c = col[i];
        int p = atomicAdd(&cur[c >> 7], 1);
        staging[p] = make_int2(row[i] | ((c & 127) << 16), __float_as_int(ew[i]));
    }
}

// B: per-bucket LDS counting sort -> csr {src, raw_ew}, ptr, deg->dis
__global__ void __launch_bounds__(256) kB(const int* __restrict__ bucketbase,
                                          const int2* __restrict__ staging,
                                          int2* __restrict__ csr, int* __restrict__ ptr,
                                          float* __restrict__ dis, int n) {
    __shared__ int2 st[BCAP];
    __shared__ int2 outb[BCAP];
    __shared__ int hist[129];
    __shared__ int cur[128];
    int k = blockIdx.x, t = threadIdx.x;
    int base = bucketbase[k], cnt = bucketbase[k + 1] - base;
    int node0 = k << 7;
    int ncov = min(128, n - node0);
    if (t < 129) hist[t] = 0;
    __syncthreads();
    if (cnt <= BCAP) {
        for (int i = t; i < cnt; i += 256) {
            int2 v = staging[base + i];
            st[i] = v;
            atomicAdd(&hist[v.x >> 16], 1);
        }
        __syncthreads();
        if (t == 0) {
            int run = 0;
            for (int j = 0; j < 128; ++j) { int h = hist[j]; hist[j] = run; run += h; }
            hist[128] = run;
        }
        __syncthreads();
        if (t < 128) cur[t] = hist[t];
        if (t < ncov) ptr[node0 + t] = base + hist[t];
        __syncthreads();
        for (int i = t; i < cnt; i += 256) {
            int2 v = st[i];
            int j = v.x >> 16;
            int p = atomicAdd(&cur[j], 1);
            outb[p] = make_int2(v.x & 0xFFFF, v.y);
        }
        __syncthreads();
        for (int i = t; i < cnt; i += 256) csr[base + i] = outb[i];
        if (t < ncov) {
            float s = 1.f;
            int a = hist[t], b2 = hist[t + 1];
            for (int p = a; p < b2; ++p) s += __int_as_float(outb[p].y);
            dis[node0 + t] = rsqrtf(s);
        }
    } else {
        // fallback (statistically unreachable): global two-sweep
        for (int i = t; i < cnt; i += 256) atomicAdd(&hist[staging[base + i].x >> 16], 1);
        __syncthreads();
        if (t == 0) {
            int run = 0;
            for (int j = 0; j < 128; ++j) { int h = hist[j]; hist[j] = run; run += h; }
            hist[128] = run;
        }
        __syncthreads();
        if (t < 128) cur[t] = hist[t];
        if (t < ncov) ptr[node0 + t] = base + hist[t];
        __syncthreads();
        for (int i = t; i < cnt; i += 256) {
            int2 v = staging[base + i];
            int j = v.x >> 16;
            int p = atomicAdd(&cur[j], 1);
            csr[base + p] = make_int2(v.x & 0xFFFF, v.y);
        }
        __threadfence_block();
        __syncthreads();
        if (t < ncov) {
            float s = 1.f;
            int a = hist[t], b2 = hist[t + 1];
            for (int p = a; p < b2; ++p) s += __int_as_float(csr[base + p].y);
            dis[node0 + t] = rsqrtf(s);
        }
    }
    if (k == gridDim.x - 1 && t == 0) ptr[n] = bucketbase[NBKT];
}

// csr[p].y: raw ew -> dis[src]*ew*dis[c]  (in place)
__global__ void k_scale(const int* __restrict__ ptr, int2* __restrict__ csr,
                        const float* __restrict__ dis, int n) {
    int i = blockIdx.x * blockDim.x + threadIdx.x;
    if (i >= n) return;
    float dc = dis[i];
    int p1 = ptr[i + 1];
    for (int p = ptr[i]; p < p1; ++p) {
        int2 v = csr[p];
        csr[p].y = __float_as_int(dis[v.x] * __int_as_float(v.y) * dc);
    }
}

// ---------------- gather ----------------
// Consumer-side BN finalize: when POSTAFF/PREAFF, each block reduces the producer's
// 16-bucket stats region (visible via stream order -- no fences) into LDS scale/shift.
// POSTAFF (L2/L3/L4): out = sc*A + sh*(dis^2 + sum w)   [BN linear, hoisted]
// PREAFF  (L5): per-edge relu(sc*u+sh)
// EPI     (L1): out = relu(A + bias), channel stats -> partOut buckets
template <int D, int POSTAFF, int PREAFF, int EPI>
__global__ void k_gather(const float* __restrict__ src, const int* __restrict__ ptr,
                         const int2* __restrict__ csr, const float* __restrict__ dis,
                         const float* __restrict__ partIn, const float* __restrict__ gmv,
                         const float* __restrict__ btv,
                         const float* __restrict__ bias, float* __restrict__ partOut,
                         float* __restrict__ out, int n) {
    const int TPN = D / 4;
    const int CONSUME = POSTAFF || PREAFF;
    __shared__ float ls[EPI ? D : 1], lq[EPI ? D : 1];
    __shared__ float scs[CONSUME ? D : 4], shs[CONSUME ? D : 4];
    int tid = threadIdx.x;
    if (EPI && tid < D) { ls[tid] = 0.f; lq[tid] = 0.f; }
    if (CONSUME && tid < D) {
        float s = 0.f, q = 0.f;
#pragma unroll
        for (int b2 = 0; b2 < NBUCKET; ++b2) {
            s += partIn[b2 * 256 + tid];
            q += partIn[b2 * 256 + 128 + tid];
        }
        float mu = s / (float)n;
        float var = q / (float)n - mu * mu;
        float a = gmv[tid] * rsqrtf(var + 1e-5f);
        scs[tid] = a;
        shs[tid] = btv[tid] - mu * a;
    }
    if (EPI || CONSUME) __syncthreads();

    int t = blockIdx.x * blockDim.x + tid;
    int node = t / TPN;
    int l4 = t - node * TPN;
    bool valid = node < n;
    int nc = valid ? node : n - 1;

    float4 sc = {0,0,0,0}, sh = {0,0,0,0};
    if (CONSUME) {
        sc = ((const float4*)scs)[l4];
        sh = ((const float4*)shs)[l4];
    }
    const float4* s4 = (const float4*)src;
    float d = dis[nc];
    float w0 = d * d;
    float4 v = s4[nc * TPN + l4];
    if (PREAFF) {
        v.x = fmaxf(sc.x * v.x + sh.x, 0.f); v.y = fmaxf(sc.y * v.y + sh.y, 0.f);
        v.z = fmaxf(sc.z * v.z + sh.z, 0.f); v.w = fmaxf(sc.w * v.w + sh.w, 0.f);
    }
    float4 acc = { w0 * v.x, w0 * v.y, w0 * v.z, w0 * v.w };
    float sumw = w0;
    int p0 = ptr[nc], p1 = ptr[nc + 1];
    int p = p0;
    for (; p + 4 <= p1; p += 4) {
        int2 c0 = csr[p], c1 = csr[p+1], c2 = csr[p+2], c3 = csr[p+3];
        float e0 = __int_as_float(c0.y), e1 = __int_as_float(c1.y);
        float e2 = __int_as_float(c2.y), e3 = __int_as_float(c3.y);
        float4 u0 = s4[c0.x * TPN + l4];
        float4 u1 = s4[c1.x * TPN + l4];
        float4 u2 = s4[c2.x * TPN + l4];
        float4 u3 = s4[c3.x * TPN + l4];
        if (PREAFF) {
            u0.x = fmaxf(sc.x*u0.x+sh.x,0.f); u0.y = fmaxf(sc.y*u0.y+sh.y,0.f);
            u0.z = fmaxf(sc.z*u0.z+sh.z,0.f); u0.w = fmaxf(sc.w*u0.w+sh.w,0.f);
            u1.x = fmaxf(sc.x*u1.x+sh.x,0.f); u1.y = fmaxf(sc.y*u1.y+sh.y,0.f);
            u1.z = fmaxf(sc.z*u1.z+sh.z,0.f); u1.w = fmaxf(sc.w*u1.w+sh.w,0.f);
            u2.x = fmaxf(sc.x*u2.x+sh.x,0.f); u2.y = fmaxf(sc.y*u2.y+sh.y,0.f);
            u2.z = fmaxf(sc.z*u2.z+sh.z,0.f); u2.w = fmaxf(sc.w*u2.w+sh.w,0.f);
            u3.x = fmaxf(sc.x*u3.x+sh.x,0.f); u3.y = fmaxf(sc.y*u3.y+sh.y,0.f);
            u3.z = fmaxf(sc.z*u3.z+sh.z,0.f); u3.w = fmaxf(sc.w*u3.w+sh.w,0.f);
        }
        acc.x += e0*u0.x + e1*u1.x + e2*u2.x + e3*u3.x;
        acc.y += e0*u0.y + e1*u1.y + e2*u2.y + e3*u3.y;
        acc.z += e0*u0.z + e1*u1.z + e2*u2.z + e3*u3.z;
        acc.w += e0*u0.w + e1*u1.w + e2*u2.w + e3*u3.w;
        if (POSTAFF) sumw += e0 + e1 + e2 + e3;
    }
    for (; p < p1; ++p) {
        int2 ce = csr[p];
        float w = __int_as_float(ce.y);
        float4 u = s4[ce.x * TPN + l4];
        if (PREAFF) {
            u.x = fmaxf(sc.x*u.x+sh.x,0.f); u.y = fmaxf(sc.y*u.y+sh.y,0.f);
            u.z = fmaxf(sc.z*u.z+sh.z,0.f); u.w = fmaxf(sc.w*u.w+sh.w,0.f);
        }
        acc.x += w*u.x; acc.y += w*u.y; acc.z += w*u.z; acc.w += w*u.w;
        if (POSTAFF) sumw += w;
    }
    if (POSTAFF) {
        acc.x = sc.x * acc.x + sh.x * sumw;
        acc.y = sc.y * acc.y + sh.y * sumw;
        acc.z = sc.z * acc.z + sh.z * sumw;
        acc.w = sc.w * acc.w + sh.w * sumw;
    }
    if (EPI) {
        float4 b = ((const float4*)bias)[l4];
        acc.x = fmaxf(acc.x + b.x, 0.f);
        acc.y = fmaxf(acc.y + b.y, 0.f);
        acc.z = fmaxf(acc.z + b.z, 0.f);
        acc.w = fmaxf(acc.w + b.w, 0.f);
        if (valid) ((float4*)out)[nc * TPN + l4] = acc;
        float s0 = valid ? acc.x : 0.f, s1 = valid ? acc.y : 0.f;
        float s2 = valid ? acc.z : 0.f, s3 = valid ? acc.w : 0.f;
        float q0 = s0*s0, q1 = s1*s1, q2 = s2*s2, q3 = s3*s3;
        for (int off = TPN; off < 64; off <<= 1) {
            s0 += __shfl_down(s0, off, 64); s1 += __shfl_down(s1, off, 64);
            s2 += __shfl_down(s2, off, 64); s3 += __shfl_down(s3, off, 64);
            q0 += __shfl_down(q0, off, 64); q1 += __shfl_down(q1, off, 64);
            q2 += __shfl_down(q2, off, 64); q3 += __shfl_down(q3, off, 64);
        }
        int lane = tid & 63;
        if (lane < TPN) {
            atomicAdd(&ls[4*lane+0], s0); atomicAdd(&ls[4*lane+1], s1);
            atomicAdd(&ls[4*lane+2], s2); atomicAdd(&ls[4*lane+3], s3);
            atomicAdd(&lq[4*lane+0], q0); atomicAdd(&lq[4*lane+1], q1);
            atomicAdd(&lq[4*lane+2], q2); atomicAdd(&lq[4*lane+3], q3);
        }
        __syncthreads();
        int bkt = (blockIdx.x & (NBUCKET - 1)) * 256;
        if (tid < D) {
            atomicAdd(&partOut[bkt + tid], ls[tid]);
            atomicAdd(&partOut[bkt + 128 + tid], lq[tid]);
        }
    } else {
        if (valid) ((float4*)out)[nc * TPN + l4] = acc;
    }
}

// ---------------- node-blocked GEMM: NPT nodes x 4 outputs per thread ----------------
template <int DIN, int DOUT, int RELU, int EPI, int NPT>
__global__ void k_gemm(const float* __restrict__ h, const float* __restrict__ W,
                       const float* __restrict__ bias, float* __restrict__ partOut,
                       float* __restrict__ m, int n) {
    const int TPN = DOUT / 4;
    const int GPB = 256 / TPN;
    __shared__ float Wl[DIN * DOUT];
    __shared__ float ls[EPI ? DOUT : 1], lq[EPI ? DOUT : 1];
    int tid = threadIdx.x;
    for (int i = tid; i < DIN * DOUT / 4; i += 256)
        ((float4*)Wl)[i] = ((const float4*)W)[i];
    if (EPI && tid < DOUT) { ls[tid] = 0.f; lq[tid] = 0.f; }
    __syncthreads();

    int jq = tid % TPN;
    int group = tid / TPN;
    int node0 = (blockIdx.x * GPB + group) * NPT;
    const float4* h4 = (const float4*)h;
    int hb[NPT];
    bool val[NPT];
#pragma unroll
    for (int i = 0; i < NPT; ++i) {
        int nd = node0 + i;
        val[i] = nd < n;
        hb[i] = (val[i] ? nd : n - 1) * (DIN / 4);
    }
    float4 acc[NPT];
#pragma unroll
    for (int i = 0; i < NPT; ++i) acc[i] = {0.f, 0.f, 0.f, 0.f};

#pragma unroll 4
    for (int k4 = 0; k4 < DIN / 4; ++k4) {
        const float* wb = &Wl[(k4 * 4) * DOUT + jq * 4];
        float4 w0 = *(const float4*)(wb);
        float4 w1 = *(const float4*)(wb + DOUT);
        float4 w2 = *(const float4*)(wb + 2 * DOUT);
        float4 w3 = *(const float4*)(wb + 3 * DOUT);
#pragma unroll
        for (int i = 0; i < NPT; ++i) {
            float4 hv = h4[hb[i] + k4];
            acc[i].x += hv.x*w0.x + hv.y*w1.x + hv.z*w2.x + hv.w*w3.x;
            acc[i].y += hv.x*w0.y + hv.y*w1.y + hv.z*w2.y + hv.w*w3.y;
            acc[i].z += hv.x*w0.z + hv.y*w1.z + hv.z*w2.z + hv.w*w3.z;
            acc[i].w += hv.x*w0.w + hv.y*w1.w + hv.z*w2.w + hv.w*w3.w;
        }
    }

    float4 bv = {0,0,0,0};
    if (EPI) bv = ((const float4*)bias)[jq];
    float4 sv = {0,0,0,0}, qv = {0,0,0,0};
#pragma unroll
    for (int i = 0; i < NPT; ++i) {
        float4 a = acc[i];
        if (EPI) {
            a.x += bv.x; a.y += bv.y; a.z += bv.z; a.w += bv.w;
            if (RELU) {
                a.x = fmaxf(a.x, 0.f); a.y = fmaxf(a.y, 0.f);
                a.z = fmaxf(a.z, 0.f); a.w = fmaxf(a.w, 0.f);
            }
        }
        if (val[i]) {
            ((float4*)m)[(node0 + i) * TPN + jq] = a;
            if (EPI) {
                sv.x += a.x; sv.y += a.y; sv.z += a.z; sv.w += a.w;
                qv.x += a.x*a.x; qv.y += a.y*a.y; qv.z += a.z*a.z; qv.w += a.w*a.w;
            }
        }
    }
    if (EPI) {
        for (int off = TPN; off < 64; off <<= 1) {
            sv.x += __shfl_down(sv.x, off, 64); sv.y += __shfl_down(sv.y, off, 64);
            sv.z += __shfl_down(sv.z, off, 64); sv.w += __shfl_down(sv.w, off, 64);
            qv.x += __shfl_down(qv.x, off, 64); qv.y += __shfl_down(qv.y, off, 64);
            qv.z += __shfl_down(qv.z, off, 64); qv.w += __shfl_down(qv.w, off, 64);
        }
        int lane = tid & 63;
        if (lane < TPN) {
            atomicAdd(&ls[4*lane+0], sv.x); atomicAdd(&ls[4*lane+1], sv.y);
            atomicAdd(&ls[4*lane+2], sv.z); atomicAdd(&ls[4*lane+3], sv.w);
            atomicAdd(&lq[4*lane+0], qv.x); atomicAdd(&lq[4*lane+1], qv.y);
            atomicAdd(&lq[4*lane+2], qv.z); atomicAdd(&lq[4*lane+3], qv.w);
        }
        __syncthreads();
        int bkt = (blockIdx.x & (NBUCKET - 1)) * 256;
        if (tid < DOUT) {
            atomicAdd(&partOut[bkt + tid], ls[tid]);
            atomicAdd(&partOut[bkt + 128 + tid], lq[tid]);
        }
    }
}

// ---------------- fused pool (BN5 consumed inline) + MLP head, atomic-free ----------------
__global__ void k_poolhead(const float* __restrict__ h, const int* __restrict__ batch,
                           const float* __restrict__ partIn, const float* __restrict__ gmv,
                           const float* __restrict__ btv,
                           const float* __restrict__ fc1w, const float* __restrict__ fc1b,
                           const float* __restrict__ fc2w, const float* __restrict__ fc2b,
                           float* __restrict__ out, int n) {
    __shared__ float tmp[256];
    __shared__ float pl[128];
    __shared__ float scs[128], shs[128];
    int g = blockIdx.x;
    int tid = threadIdx.x;
    if (tid < 128) {
        float s = 0.f, q = 0.f;
#pragma unroll
        for (int b2 = 0; b2 < NBUCKET; ++b2) {
            s += partIn[b2 * 256 + tid];
            q += partIn[b2 * 256 + 128 + tid];
        }
        float mu = s / (float)n;
        float var = q / (float)n - mu * mu;
        float a = gmv[tid] * rsqrtf(var + 1e-5f);
        scs[tid] = a;
        shs[tid] = btv[tid] - mu * a;
    }
    int j = tid & 127, prt = tid >> 7;
    int a = 0, b = n;
    while (a < b) { int mid = (a + b) >> 1; if (batch[mid] < g) a = mid + 1; else b = mid; }
    int lo = a;
    b = n;
    while (a < b) { int mid = (a + b) >> 1; if (batch[mid] < g + 1) a = mid + 1; else b = mid; }
    int hi = a;

    float acc = 0.f;
    for (int node = lo + prt; node < hi; node += 2) acc += h[(long)node * 128 + j];
    tmp[tid] = acc;
    __syncthreads();
    if (tid < 128) {
        float cnt = (float)(hi - lo);
        float p = scs[tid] * (tmp[tid] + tmp[tid + 128]) + shs[tid] * cnt;
        pl[tid] = fmaxf(p, 0.f);
    }
    __syncthreads();
    if (tid < 64) {
        float v1 = fc1b[tid];
        for (int k = 0; k < 128; ++k) v1 += pl[k] * fc1w[k * 64 + tid];
        v1 = fmaxf(v1, 0.f);
        float v = v1 * fc2w[tid];
        for (int off = 32; off > 0; off >>= 1) v += __shfl_down(v, off, 64);
        if (tid == 0) out[g] = v + fc2b[0];
    }
}

// ---------------- driver ----------------
extern "C" void kernel_launch(void* const* d_in, const int* in_sizes, int n_in,
                              void* d_out, int out_size, void* d_ws, size_t ws_size,
                              hipStream_t stream) {
    const float* x     = (const float*)d_in[0];
    const int*   ei    = (const int*)d_in[1];
    const float* ew    = (const float*)d_in[2];
    const int*   batch = (const int*)d_in[3];
    const float *W[5], *b[5], *gm[5], *bt[5];
    for (int i = 0; i < 5; ++i) {
        W[i]  = (const float*)d_in[4 + 4 * i];
        b[i]  = (const float*)d_in[5 + 4 * i];
        gm[i] = (const float*)d_in[6 + 4 * i];
        bt[i] = (const float*)d_in[7 + 4 * i];
    }
    const float* fc1w = (const float*)d_in[24];
    const float* fc1b = (const float*)d_in[25];
    const float* fc2w = (const float*)d_in[26];
    const float* fc2b = (const float*)d_in[27];
    float* out = (float*)d_out;

    // workspace layout
    char* wsb = (char*)d_ws;
    float* dis    = (float*)wsb;  wsb += sizeof(float) * NN;
    int*   ptr    = (int*)wsb;    wsb += sizeof(int) * (NN + 4);
    int*   bb     = (int*)wsb;    wsb += sizeof(int) * ABLK * NBKT;
    int*   totals = (int*)wsb;    wsb += sizeof(int) * (NBKT + 1);
    int*   bbase  = (int*)wsb;    wsb += sizeof(int) * (NBKT + 3);
    int2*  staging= (int2*)wsb;   wsb += sizeof(int2) * NE;
    int2*  csr    = (int2*)wsb;   wsb += sizeof(int2) * NE;
    float* part   = (float*)wsb;  wsb += sizeof(float) * 5 * PARTSZ;
    float* buf1   = (float*)wsb;  wsb += sizeof(float) * (long)NN * 128;
    float* buf2   = (float*)wsb;  wsb += sizeof(float) * (long)NN * 128;

    const int* row = ei;
    const int* col = ei + NE;
    const int B = 256;
    const int NB_N = (NN + B - 1) / B;   // 196

    // prologue: bucketed CSR build (atomic-light, coalesced)
    k_init<<<(5 * PARTSZ + B - 1) / B, B, 0, stream>>>(part);
    kA1<<<ABLK, B, 0, stream>>>(col, bb, NE);
    kA2a<<<NBKT, B, 0, stream>>>(bb, totals);
    kA2b<<<1, B, 0, stream>>>(totals, bbase);
    kA3<<<ABLK, B, 0, stream>>>(row, col, ew, bb, bbase, staging, NE);
    kB<<<NBKT, B, 0, stream>>>(bbase, staging, csr, ptr, dis, NN);
    k_scale<<<NB_N, B, 0, stream>>>(ptr, csr, dis, NN);

    auto grid4 = [](long threads) { return (int)((threads + 255) / 256); };
    auto ggrid = [](int npb) { return (NN + npb - 1) / npb; };

    // L1: gemm 128->16 (NPT=2), gather16 + bias+relu+stats (produce part[0])
    k_gemm<128, 16, 0, 0, 2><<<ggrid((256/4)*2), B, 0, stream>>>(x, W[0], b[0], nullptr, buf1, NN);
    k_gather<16, 0, 0, 1><<<grid4((long)NN * 4), B, 0, stream>>>(buf1, ptr, csr, dis,
                                                                 nullptr, nullptr, nullptr,
                                                                 b[0], part + 0 * PARTSZ, buf2, NN);

    // L2: gather16 (consume part[0] -> BN1 hoisted), gemm 16->32 (produce part[1])
    k_gather<16, 1, 0, 0><<<grid4((long)NN * 4), B, 0, stream>>>(buf2, ptr, csr, dis,
                                                                 part + 0 * PARTSZ, gm[0], bt[0],
                                                                 nullptr, nullptr, buf1, NN);
    k_gemm<16, 32, 1, 1, 4><<<ggrid((256/8)*4), B, 0, stream>>>(buf1, W[1], b[1], part + 1 * PARTSZ, buf2, NN);

    // L3: gather32 (consume part[1]), gemm 32->64 (produce part[2])
    k_gather<32, 1, 0, 0><<<grid4((long)NN * 8), B, 0, stream>>>(buf2, ptr, csr, dis,
                                                                 part + 1 * PARTSZ, gm[1], bt[1],
                                                                 nullptr, nullptr, buf1, NN);
    k_gemm<32, 64, 1, 1, 4><<<ggrid((256/16)*4), B, 0, stream>>>(buf1, W[2], b[2], part + 2 * PARTSZ, buf2, NN);

    // L4: gather64 (consume part[2]), gemm 64->64 (produce part[3]; relu post-BN)
    k_gather<64, 1, 0, 0><<<grid4((long)NN * 16), B, 0, stream>>>(buf2, ptr, csr, dis,
                                                                  part + 2 * PARTSZ, gm[2], bt[2],
                                                                  nullptr, nullptr, buf1, NN);
    k_gemm<64, 64, 0, 1, 4><<<ggrid((256/16)*4), B, 0, stream>>>(buf1, W[3], b[3], part + 3 * PARTSZ, buf2, NN);

    // L5: gather64 (consume part[3]; BN4 + relu per-edge), gemm 64->128 (produce part[4])
    k_gather<64, 0, 1, 0><<<grid4((long)NN * 16), B, 0, stream>>>(buf2, ptr, csr, dis,
                                                                  part + 3 * PARTSZ, gm[3], bt[3],
                                                                  nullptr, nullptr, buf1, NN);
    k_gemm<64, 128, 0, 1, 4><<<ggrid((256/32)*4), B, 0, stream>>>(buf1, W[4], b[4], part + 4 * PARTSZ, buf2, NN);

    // fused pool (consume part[4] -> BN5) + head
    k_poolhead<<<NG, 256, 0, stream>>>(buf2, batch, part + 4 * PARTSZ, gm[4], bt[4],
                                       fc1w, fc1b, fc2w, fc2b, out, NN);
}